// Round 3
// baseline (4365.722 us; speedup 1.0000x reference)
//
#include <hip/hip_runtime.h>

// ---- dims (fixed by problem) ----
#define B    32
#define P    196
#define ENC  2048
#define DEC  512
#define ATT  512
#define E    256
#define V    30000
#define VPAD 30080   // V padded to multiple of 128 for the final GEMM
#define L    21
#define T    20      // L-1
#define KX   2304    // E + ENC
#define GRID 256     // persistent-kernel grid (1 block/CU guaranteed resident)

typedef unsigned short u16;
typedef __bf16 bf16x8 __attribute__((ext_vector_type(8)));
typedef float  f32x4  __attribute__((ext_vector_type(4)));

__device__ __forceinline__ u16 f2bf(float f) {
    union { float f; unsigned int i; } v; v.f = f;
    unsigned int i = v.i;
    return (u16)((i + 0x7fffu + ((i >> 16) & 1u)) >> 16);
}
__device__ __forceinline__ float bf2f(u16 u) {
    union { unsigned int i; float f; } v; v.i = ((unsigned int)u) << 16; return v.f;
}
__device__ __forceinline__ float wave_sum(float v) {
    #pragma unroll
    for (int o = 32; o > 0; o >>= 1) v += __shfl_down(v, o, 64);
    return v;  // lane 0 holds sum
}
__device__ __forceinline__ float sigf(float x) { return 1.0f / (1.0f + expf(-x)); }

// bijective XCD swizzle (m204): consecutive logical ids land on the same XCD
__device__ __forceinline__ int xcd_swizzle(int bid, int nwg) {
    int xcd = bid & 7, idx = bid >> 3;
    int q = nwg >> 3, r = nwg & 7;
    return (xcd < r ? xcd * (q + 1) : r * (q + 1) + (xcd - r) * q) + idx;
}

// async global->LDS, 16B per lane; LDS dest is wave-uniform base + lane*16
__device__ __forceinline__ void gl2lds16(const u16* g, char* l) {
    __builtin_amdgcn_global_load_lds(
        (const __attribute__((address_space(1))) void*)g,
        (__attribute__((address_space(3))) void*)l, 16, 0, 0);
}

// ---- software grid barrier (sense-reversing, device-scope) ----
// bar[0] = arrive counter, bar[1] = generation
__device__ __forceinline__ void gsync(int* bar) {
    __syncthreads();                 // drains this block's vmem stores to L2
    if (threadIdx.x == 0) {
        __threadfence();             // release: flush L2 to device coherence point
        int gen  = __hip_atomic_load(bar + 1, __ATOMIC_RELAXED, __HIP_MEMORY_SCOPE_AGENT);
        int prev = __hip_atomic_fetch_add(bar, 1, __ATOMIC_ACQ_REL, __HIP_MEMORY_SCOPE_AGENT);
        if (prev == GRID - 1) {      // last arriver releases
            __hip_atomic_store(bar, 0, __ATOMIC_RELAXED, __HIP_MEMORY_SCOPE_AGENT);
            __hip_atomic_store(bar + 1, gen + 1, __ATOMIC_RELEASE, __HIP_MEMORY_SCOPE_AGENT);
        } else {
            while (__hip_atomic_load(bar + 1, __ATOMIC_ACQUIRE, __HIP_MEMORY_SCOPE_AGENT) == gen)
                __builtin_amdgcn_s_sleep(4);
        }
        __threadfence();             // acquire: invalidate L1/L2 for fresh reads
    }
    __syncthreads();
}

__global__ void k_init_bar(int* bar) { if (threadIdx.x < 2) bar[threadIdx.x] = 0; }

// ---- once: f32 -> bf16 conversion (4 elems/thread) ----
__global__ void k_f2b4(const float* __restrict__ s, u16* __restrict__ d, int n4) {
    int i = blockIdx.x * 256 + threadIdx.x;
    if (i < n4) {
        float4 v = reinterpret_cast<const float4*>(s)[i];
        ushort4 o;
        o.x = f2bf(v.x); o.y = f2bf(v.y); o.z = f2bf(v.z); o.w = f2bf(v.w);
        reinterpret_cast<ushort4*>(d)[i] = o;
    }
}

__global__ void k_zero16(u16* __restrict__ d, int n) {
    int i = blockIdx.x * 256 + threadIdx.x;
    if (i < n) d[i] = 0;
}

// ---- once: mean over P of encoder_out (f32) -> f32 [B,ENC] ----
__global__ void k_mean(const float* __restrict__ enc, float* __restrict__ mean) {
    int idx = blockIdx.x * 256 + threadIdx.x;        // 65536
    int b = idx >> 11, e = idx & 2047;
    const float* p = enc + (size_t)b * P * ENC + e;
    float s = 0.f;
    for (int i = 0; i < P; i++) s += p[(size_t)i * ENC];
    mean[idx] = s * (1.0f / 196.0f);
}

// ---- once: h0/c0 = mean @ W^T + b  (f32 dot, wave per output) ----
__global__ void k_h0c0(const float* __restrict__ mean,
                       const float* __restrict__ Wh0, const float* __restrict__ bh0,
                       const float* __restrict__ Wc0, const float* __restrict__ bc0,
                       u16* __restrict__ h, float* __restrict__ c) {
    int wid = (blockIdx.x * 256 + threadIdx.x) >> 6;
    int lane = threadIdx.x & 63;
    int b = wid >> 10, j = wid & 1023;
    bool is_h = j < DEC;
    int jj = is_h ? j : j - DEC;
    const float* W = is_h ? Wh0 : Wc0;
    const float* mrow = mean + b * ENC;
    const float* wrow = W + (size_t)jj * ENC;
    float acc = 0.f;
    #pragma unroll
    for (int kk = 0; kk < 4; kk++) {
        int k = kk * 512 + lane * 8;
        float4 a0 = *reinterpret_cast<const float4*>(mrow + k);
        float4 a1 = *reinterpret_cast<const float4*>(mrow + k + 4);
        float4 w0 = *reinterpret_cast<const float4*>(wrow + k);
        float4 w1 = *reinterpret_cast<const float4*>(wrow + k + 4);
        acc += a0.x * w0.x + a0.y * w0.y + a0.z * w0.z + a0.w * w0.w;
        acc += a1.x * w1.x + a1.y * w1.y + a1.z * w1.z + a1.w * w1.w;
    }
    acc = wave_sum(acc);
    if (lane == 0) {
        acc += is_h ? bh0[jj] : bc0[jj];
        if (is_h) h[b * DEC + jj] = f2bf(acc);
        else      c[b * DEC + jj] = acc;
    }
}

// ---- tiled 128x128 GEMM, BK=64, 4 waves, global_load_lds + XOR swizzle ----
// C[M,N] = A[M,K] @ Bmat[N,K]^T + bias.  Row-major bf16 A/B, K elems/row.
template<int K, bool PREDS>
__global__ __launch_bounds__(256) void k_gemm128(
        const u16* __restrict__ A, const u16* __restrict__ Bmat,
        const float* __restrict__ bias, float* __restrict__ Cout) {
    __shared__ char smem[32768];
    char* As = smem;            // [128 rows][128 B], swizzled
    char* Bs = smem + 16384;
    int g = xcd_swizzle(blockIdx.x, gridDim.x);
    int bm, bn;
    if constexpr (PREDS) { bm = g % 5; bn = g / 5; }   // B-panel reuse across 5 m-blocks
    else                 { bm = g >> 2; bn = g & 3; }  // A-panel reuse across 4 n-blocks
    int tid  = threadIdx.x;
    int w    = tid >> 6, lane = tid & 63;
    int quad = lane >> 4, l16 = lane & 15;
    int wave_m = (w >> 1) * 64, wave_n = (w & 1) * 64;

    // staging: phys LDS slot o = i*4096 + w*1024 + lane*16
    // phys row r = o>>7; source col-byte = (o&127) ^ ((r&7)<<4)  (involution)
    int rl = lane >> 3;                        // r&7
    int ce = (((lane & 7) << 4) ^ (rl << 4)) >> 1;   // element offset in row
    const u16* srcA[4]; const u16* srcB[4];
    char* dstA[4]; char* dstB[4];
    #pragma unroll
    for (int i = 0; i < 4; i++) {
        int r = i * 32 + w * 8 + rl;
        srcA[i] = A    + (size_t)(bm * 128 + r) * K + ce;
        srcB[i] = Bmat + (size_t)(bn * 128 + r) * K + ce;
        dstA[i] = As + i * 4096 + w * 1024;
        dstB[i] = Bs + i * 4096 + w * 1024;
    }

    f32x4 acc[4][4] = {};
    int swz = (l16 & 7) << 4;
    for (int kt = 0; kt < K / 64; kt++) {
        int koff = kt * 64;
        #pragma unroll
        for (int i = 0; i < 4; i++) {
            gl2lds16(srcA[i] + koff, dstA[i]);
            gl2lds16(srcB[i] + koff, dstB[i]);
        }
        __syncthreads();
        #pragma unroll
        for (int ks = 0; ks < 2; ks++) {
            int cb = ks * 64 + quad * 16;
            bf16x8 av[4], bv[4];
            #pragma unroll
            for (int mi = 0; mi < 4; mi++) {
                int r = wave_m + mi * 16 + l16;
                av[mi] = *reinterpret_cast<const bf16x8*>(As + r * 128 + (cb ^ swz));
            }
            #pragma unroll
            for (int ni = 0; ni < 4; ni++) {
                int r = wave_n + ni * 16 + l16;
                bv[ni] = *reinterpret_cast<const bf16x8*>(Bs + r * 128 + (cb ^ swz));
            }
            #pragma unroll
            for (int mi = 0; mi < 4; mi++)
                #pragma unroll
                for (int ni = 0; ni < 4; ni++)
                    acc[mi][ni] = __builtin_amdgcn_mfma_f32_16x16x32_bf16(
                        av[mi], bv[ni], acc[mi][ni], 0, 0, 0);
        }
        __syncthreads();
    }

    #pragma unroll
    for (int mi = 0; mi < 4; mi++) {
        #pragma unroll
        for (int ni = 0; ni < 4; ni++) {
            int nn = bn * 128 + wave_n + ni * 16 + l16;
            float bv = (!PREDS || nn < V) ? bias[nn] : 0.f;
            #pragma unroll
            for (int r = 0; r < 4; r++) {
                int mm = bm * 128 + wave_m + mi * 16 + quad * 4 + r;
                if constexpr (PREDS) {
                    if (nn < V) {
                        int b = mm & 31, t = mm >> 5;   // row = t*B + b
                        Cout[(size_t)b * T * V + (size_t)t * V + nn] = acc[mi][ni][r] + bv;
                    }
                } else {
                    Cout[(size_t)mm * ATT + nn] = acc[mi][ni][r] + bv;
                }
            }
        }
    }
}

// ---- persistent kernel: all 20 decode steps (software grid barrier) ----
// grid = 256 blocks x 256 threads (1 block/CU, trivially co-resident)
__global__ __launch_bounds__(256) void k_decode(
        const u16* __restrict__ enc_bf, const float* __restrict__ att1,
        const float* __restrict__ Wd,   const float* __restrict__ bd,
        const float* __restrict__ Wf,   const float* __restrict__ bfa,
        const float* __restrict__ emb,  const int* __restrict__ caps,
        const u16* __restrict__ Wih,    const float* __restrict__ bih,
        const u16* __restrict__ Whh,    const float* __restrict__ bhh,
        u16* __restrict__ hb0, u16* __restrict__ hb1,
        float* __restrict__ cbuf, u16* __restrict__ hall,
        float* __restrict__ att2w, float* __restrict__ ew,
        u16* __restrict__ xbuf, float* __restrict__ gpart,
        float* __restrict__ out_alpha, int* bar)
{
    __shared__ float sm[256];
    __shared__ float al[256];
    const int tid  = threadIdx.x;
    const int bid  = blockIdx.x;
    const int gtid = bid * 256 + tid;
    const int wid  = gtid >> 6;        // 0..1023
    const int lane = tid & 63;

    // step-invariant loads
    const float4 wf0 = *reinterpret_cast<const float4*>(Wf + (lane << 3));
    const float4 wf1 = *reinterpret_cast<const float4*>(Wf + (lane << 3) + 4);
    const float  bf0 = bfa[0];

    for (int t = 0; t < T; t++) {
        const u16* h  = (t & 1) ? hb1 : hb0;
        u16*       hn = (t & 1) ? hb0 : hb1;

        // ---- A: att2w[o] = h[b,:]·Wd[a,:] + bd[a], o = b*512+a ----
        {
            int o0 = wid * 16;            // 16 outputs per wave, same b
            int b  = o0 >> 9;
            bf16x8 hv = *reinterpret_cast<const bf16x8*>(h + b * DEC + (lane << 3));
            float hf[8];
            #pragma unroll
            for (int j = 0; j < 8; j++) hf[j] = (float)hv[j];
            #pragma unroll 4
            for (int i = 0; i < 16; i++) {
                int a = (o0 & 511) + i;
                const float* wd = Wd + (size_t)a * DEC + (lane << 3);
                float4 w0 = *reinterpret_cast<const float4*>(wd);
                float4 w1 = *reinterpret_cast<const float4*>(wd + 4);
                float acc = hf[0]*w0.x + hf[1]*w0.y + hf[2]*w0.z + hf[3]*w0.w
                          + hf[4]*w1.x + hf[5]*w1.y + hf[6]*w1.z + hf[7]*w1.w;
                acc = wave_sum(acc);
                if (lane == 0) att2w[o0 + i] = acc + bd[a];
            }
        }
        gsync(bar);

        // ---- B: ew[o] = sum_a relu(att1[b,p,a]+att2[b,a])*Wf[a] + bf ----
        for (int o = wid; o < B * P; o += 1024) {
            int b = o / P;
            const float* s = att2w + (b << 9) + (lane << 3);
            float4 s0 = *reinterpret_cast<const float4*>(s);
            float4 s1 = *reinterpret_cast<const float4*>(s + 4);
            const float* a1 = att1 + (size_t)o * ATT + (lane << 3);
            float4 x0 = *reinterpret_cast<const float4*>(a1);
            float4 x1 = *reinterpret_cast<const float4*>(a1 + 4);
            float acc;
            acc  = fmaxf(x0.x + s0.x, 0.f) * wf0.x;
            acc += fmaxf(x0.y + s0.y, 0.f) * wf0.y;
            acc += fmaxf(x0.z + s0.z, 0.f) * wf0.z;
            acc += fmaxf(x0.w + s0.w, 0.f) * wf0.w;
            acc += fmaxf(x1.x + s1.x, 0.f) * wf1.x;
            acc += fmaxf(x1.y + s1.y, 0.f) * wf1.y;
            acc += fmaxf(x1.z + s1.z, 0.f) * wf1.z;
            acc += fmaxf(x1.w + s1.w, 0.f) * wf1.w;
            acc = wave_sum(acc);
            if (lane == 0) ew[o] = acc + bf0;
        }
        gsync(bar);

        // ---- CD: softmax (redundant per 8-block group) + awe + x build ----
        {
            int b = bid >> 3, chunk = bid & 7;
            float v = (tid < P) ? ew[b * P + tid] : -1e30f;
            sm[tid] = v; __syncthreads();
            for (int s = 128; s > 0; s >>= 1) {
                if (tid < s) sm[tid] = fmaxf(sm[tid], sm[tid + s]);
                __syncthreads();
            }
            float mx = sm[0]; __syncthreads();
            float evv = (tid < P) ? expf(v - mx) : 0.f;
            sm[tid] = evv; __syncthreads();
            for (int s = 128; s > 0; s >>= 1) {
                if (tid < s) sm[tid] += sm[tid + s];
                __syncthreads();
            }
            float inv = 1.0f / sm[0];
            float aa = evv * inv;                 // 0 for tid >= P
            al[tid] = aa;
            if (chunk == 0 && tid < P)
                out_alpha[(size_t)b * T * P + (size_t)t * P + tid] = aa;
            __syncthreads();
            int ec = (chunk << 8) + tid;
            const u16* ep = enc_bf + (size_t)b * P * ENC + ec;
            float acc = 0.f;
            #pragma unroll 4
            for (int p = 0; p < P; p++) acc += al[p] * bf2f(ep[(size_t)p * ENC]);
            xbuf[b * KX + E + ec] = f2bf(acc);
            if (chunk == 0) {
                int cap = caps[b * L + t];
                xbuf[b * KX + tid] = f2bf(emb[(size_t)cap * E + tid]);
            }
        }
        gsync(bar);

        // ---- E1: gates partials, 4-way K-split.  bid = kq*64 + mt*32 + jt ----
        {
            int kq = bid >> 6, mt = (bid >> 5) & 1, jt = bid & 31;
            int wg = tid >> 6;                       // gate section 0..3
            int quad = lane >> 4, l16 = lane & 15;
            int m = mt * 16 + l16;
            int n = (wg << 9) + (jt << 4) + l16;     // 0..2047
            f32x4 acc = {0.f, 0.f, 0.f, 0.f};
            int k0 = kq * 704;                       // 704*4 = 2816 = KX + DEC
            for (int ks = 0; ks < 22; ks++) {
                int kb = k0 + ks * 32;
                bf16x8 av, bv;
                if (kb < KX) {
                    av = *reinterpret_cast<const bf16x8*>(xbuf + m * KX + kb + (quad << 3));
                    bv = *reinterpret_cast<const bf16x8*>(Wih + (size_t)n * KX + kb + (quad << 3));
                } else {
                    av = *reinterpret_cast<const bf16x8*>(h + m * DEC + (kb - KX) + (quad << 3));
                    bv = *reinterpret_cast<const bf16x8*>(Whh + (size_t)n * DEC + (kb - KX) + (quad << 3));
                }
                acc = __builtin_amdgcn_mfma_f32_16x16x32_bf16(av, bv, acc, 0, 0, 0);
            }
            #pragma unroll
            for (int r = 0; r < 4; r++) {
                int gm = mt * 16 + (quad << 2) + r;
                gpart[((kq << 5) + gm) * 2048 + n] = acc[r];
            }
        }
        gsync(bar);

        // ---- E2: reduce partials + LSTM cell ----
        if (gtid < B * DEC) {
            int d = gtid & 511;
            int b = gtid >> 9;
            float g0 = bih[d]        + bhh[d];
            float g1 = bih[512 + d]  + bhh[512 + d];
            float g2 = bih[1024 + d] + bhh[1024 + d];
            float g3 = bih[1536 + d] + bhh[1536 + d];
            #pragma unroll
            for (int kq = 0; kq < 4; kq++) {
                const float* gp = gpart + ((kq << 5) + b) * 2048;
                g0 += gp[d]; g1 += gp[512 + d]; g2 += gp[1024 + d]; g3 += gp[1536 + d];
            }
            float gi = sigf(g0), gf = sigf(g1), gg = tanhf(g2), go = sigf(g3);
            float cn = gf * cbuf[gtid] + gi * gg;
            cbuf[gtid] = cn;
            u16 hbv = f2bf(go * tanhf(cn));
            hn[gtid] = hbv;
            hall[(size_t)t * B * DEC + gtid] = hbv;
        }
        gsync(bar);
    }
}

extern "C" void kernel_launch(void* const* d_in, const int* in_sizes, int n_in,
                              void* d_out, int out_size, void* d_ws, size_t ws_size,
                              hipStream_t stream) {
    const float* enc  = (const float*)d_in[0];
    const int*   caps = (const int*)d_in[1];
    // d_in[2] caption_lengths: unused by reference output
    const float* emb  = (const float*)d_in[3];
    const float* We   = (const float*)d_in[4];
    const float* be   = (const float*)d_in[5];
    const float* Wd   = (const float*)d_in[6];
    const float* bd   = (const float*)d_in[7];
    const float* Wf   = (const float*)d_in[8];
    const float* bfa  = (const float*)d_in[9];
    const float* Wih  = (const float*)d_in[10];
    const float* bih  = (const float*)d_in[11];
    const float* Whh  = (const float*)d_in[12];
    const float* bhh  = (const float*)d_in[13];
    const float* Wfc  = (const float*)d_in[14];
    const float* bfc  = (const float*)d_in[15];
    const float* Wh0  = (const float*)d_in[16];
    const float* bh0  = (const float*)d_in[17];
    const float* Wc0  = (const float*)d_in[18];
    const float* bc0  = (const float*)d_in[19];

    float* out_preds = (float*)d_out;
    float* out_alpha = (float*)d_out + (size_t)B * T * V;

    char* w = (char*)d_ws;
    size_t off = 0;
    auto carve = [&](size_t bytes) -> void* {
        void* p = w + off;
        off = (off + bytes + 255) & ~(size_t)255;
        return p;
    };
    u16*   enc_bf = (u16*)  carve((size_t)B * P * ENC * 2);        // 25.7 MB
    u16*   We_bf  = (u16*)  carve((size_t)ATT * ENC * 2);          //  2.1 MB
    u16*   Wih_bf = (u16*)  carve((size_t)4 * DEC * KX * 2);       //  9.4 MB
    u16*   Whh_bf = (u16*)  carve((size_t)4 * DEC * DEC * 2);      //  2.1 MB
    u16*   Wfc_bf = (u16*)  carve((size_t)VPAD * DEC * 2);         // 30.8 MB (padded)
    float* att1   = (float*)carve((size_t)B * P * ATT * 4);        // 12.85 MB
    float* meanb  = (float*)carve((size_t)B * ENC * 4);
    float* att2w  = (float*)carve((size_t)B * ATT * 4);
    float* ew     = (float*)carve((size_t)B * P * 4);
    u16*   xbuf   = (u16*)  carve((size_t)B * KX * 2);
    u16*   hb0    = (u16*)  carve((size_t)B * DEC * 2);
    u16*   hb1    = (u16*)  carve((size_t)B * DEC * 2);
    float* cbuf   = (float*)carve((size_t)B * DEC * 4);
    u16*   hall   = (u16*)  carve((size_t)T * B * DEC * 2);        // 0.66 MB
    float* gpart  = (float*)carve((size_t)4 * B * 4 * DEC * 4);    // 1 MB
    int*   bar    = (int*)  carve(256);
    (void)ws_size; (void)n_in; (void)in_sizes; (void)out_size;

    // one-time: bf16 conversions + barrier init
    k_init_bar<<<1, 64, 0, stream>>>(bar);
    k_f2b4<<<(B * P * ENC) / 1024, 256, 0, stream>>>(enc, enc_bf, (B * P * ENC) / 4);
    k_f2b4<<<(ATT * ENC) / 1024, 256, 0, stream>>>(We, We_bf, (ATT * ENC) / 4);
    k_f2b4<<<(4 * DEC * KX) / 1024, 256, 0, stream>>>(Wih, Wih_bf, (4 * DEC * KX) / 4);
    k_f2b4<<<(4 * DEC * DEC) / 1024, 256, 0, stream>>>(Whh, Whh_bf, (4 * DEC * DEC) / 4);
    k_f2b4<<<(V * DEC) / 1024, 256, 0, stream>>>(Wfc, Wfc_bf, (V * DEC) / 4);
    k_zero16<<<((VPAD - V) * DEC) / 256, 256, 0, stream>>>(Wfc_bf + (size_t)V * DEC, (VPAD - V) * DEC);

    // init phase
    k_mean<<<(B * ENC) / 256, 256, 0, stream>>>(enc, meanb);
    k_h0c0<<<(B * 2 * DEC * 64) / 256, 256, 0, stream>>>(meanb, Wh0, bh0, Wc0, bc0, hb0, cbuf);
    // att1 = enc @ We^T + be : [6272, 2048] x [512, 2048]^T, tiled GEMM
    k_gemm128<ENC, false><<<(B * P / 128) * (ATT / 128), 256, 0, stream>>>(enc_bf, We_bf, be, att1);

    // all 20 decode steps in one persistent kernel (normal launch, graph-capturable)
    k_decode<<<GRID, 256, 0, stream>>>(
        enc_bf, att1, Wd, bd, Wf, bfa, emb, caps, Wih_bf, bih, Whh_bf, bhh,
        hb0, hb1, cbuf, hall, att2w, ew, xbuf, gpart, out_alpha, bar);

    // batched preds: [T*B, DEC] @ Wfc^T -> out[b, t, :]
    k_gemm128<DEC, true><<<5 * (VPAD / 128), 256, 0, stream>>>(hall, Wfc_bf, bfc, out_preds);
}

// Round 4
// 1155.104 us; speedup vs baseline: 3.7795x; 3.7795x over previous
//
#include <hip/hip_runtime.h>

// ---- dims (fixed by problem) ----
#define B    32
#define P    196
#define ENC  2048
#define DEC  512
#define ATT  512
#define E    256
#define V    30000
#define VPAD 30080   // V padded to multiple of 128 for the final GEMM
#define L    21
#define T    20      // L-1
#define KX   2304    // E + ENC

typedef unsigned short u16;
typedef __bf16 bf16x8 __attribute__((ext_vector_type(8)));
typedef float  f32x4  __attribute__((ext_vector_type(4)));

__device__ __forceinline__ u16 f2bf(float f) {
    union { float f; unsigned int i; } v; v.f = f;
    unsigned int i = v.i;
    return (u16)((i + 0x7fffu + ((i >> 16) & 1u)) >> 16);
}
__device__ __forceinline__ float bf2f(u16 u) {
    union { unsigned int i; float f; } v; v.i = ((unsigned int)u) << 16; return v.f;
}
__device__ __forceinline__ float wave_sum(float v) {
    #pragma unroll
    for (int o = 32; o > 0; o >>= 1) v += __shfl_down(v, o, 64);
    return v;  // lane 0 holds sum
}
__device__ __forceinline__ float sigf(float x) { return 1.0f / (1.0f + expf(-x)); }

// bijective XCD swizzle (m204)
__device__ __forceinline__ int xcd_swizzle(int bid, int nwg) {
    int xcd = bid & 7, idx = bid >> 3;
    int q = nwg >> 3, r = nwg & 7;
    return (xcd < r ? xcd * (q + 1) : r * (q + 1) + (xcd - r) * q) + idx;
}

// async global->LDS, 16B per lane
__device__ __forceinline__ void gl2lds16(const u16* g, char* l) {
    __builtin_amdgcn_global_load_lds(
        (const __attribute__((address_space(1))) void*)g,
        (__attribute__((address_space(3))) void*)l, 16, 0, 0);
}

// ---- once: f32 -> bf16 conversion (4 elems/thread) ----
__global__ void k_f2b4(const float* __restrict__ s, u16* __restrict__ d, int n4) {
    int i = blockIdx.x * 256 + threadIdx.x;
    if (i < n4) {
        float4 v = reinterpret_cast<const float4*>(s)[i];
        ushort4 o;
        o.x = f2bf(v.x); o.y = f2bf(v.y); o.z = f2bf(v.z); o.w = f2bf(v.w);
        reinterpret_cast<ushort4*>(d)[i] = o;
    }
}

__global__ void k_zero16(u16* __restrict__ d, int n) {
    int i = blockIdx.x * 256 + threadIdx.x;
    if (i < n) d[i] = 0;
}

// ---- once: mean over P of encoder_out (f32) -> f32 [B,ENC] ----
__global__ void k_mean(const float* __restrict__ enc, float* __restrict__ mean) {
    int idx = blockIdx.x * 256 + threadIdx.x;        // 65536
    int b = idx >> 11, e = idx & 2047;
    const float* p = enc + (size_t)b * P * ENC + e;
    float s = 0.f;
    for (int i = 0; i < P; i++) s += p[(size_t)i * ENC];
    mean[idx] = s * (1.0f / 196.0f);
}

// ---- once: h0/c0 = mean @ W^T + b ----
__global__ void k_h0c0(const float* __restrict__ mean,
                       const float* __restrict__ Wh0, const float* __restrict__ bh0,
                       const float* __restrict__ Wc0, const float* __restrict__ bc0,
                       u16* __restrict__ h, float* __restrict__ c) {
    int wid = (blockIdx.x * 256 + threadIdx.x) >> 6;
    int lane = threadIdx.x & 63;
    int b = wid >> 10, j = wid & 1023;
    bool is_h = j < DEC;
    int jj = is_h ? j : j - DEC;
    const float* W = is_h ? Wh0 : Wc0;
    const float* mrow = mean + b * ENC;
    const float* wrow = W + (size_t)jj * ENC;
    float acc = 0.f;
    #pragma unroll
    for (int kk = 0; kk < 4; kk++) {
        int k = kk * 512 + lane * 8;
        float4 a0 = *reinterpret_cast<const float4*>(mrow + k);
        float4 a1 = *reinterpret_cast<const float4*>(mrow + k + 4);
        float4 w0 = *reinterpret_cast<const float4*>(wrow + k);
        float4 w1 = *reinterpret_cast<const float4*>(wrow + k + 4);
        acc += a0.x * w0.x + a0.y * w0.y + a0.z * w0.z + a0.w * w0.w;
        acc += a1.x * w1.x + a1.y * w1.y + a1.z * w1.z + a1.w * w1.w;
    }
    acc = wave_sum(acc);
    if (lane == 0) {
        acc += is_h ? bh0[jj] : bc0[jj];
        if (is_h) h[b * DEC + jj] = f2bf(acc);
        else      c[b * DEC + jj] = acc;
    }
}

// ---- tiled 128x128 GEMM, BK=64, global_load_lds + XOR swizzle ----
template<int K, bool PREDS>
__global__ __launch_bounds__(256) void k_gemm128(
        const u16* __restrict__ A, const u16* __restrict__ Bmat,
        const float* __restrict__ bias, float* __restrict__ Cout) {
    __shared__ char smem[32768];
    char* As = smem;
    char* Bs = smem + 16384;
    int g = xcd_swizzle(blockIdx.x, gridDim.x);
    int bm, bn;
    if constexpr (PREDS) { bm = g % 5; bn = g / 5; }
    else                 { bm = g >> 2; bn = g & 3; }
    int tid  = threadIdx.x;
    int w    = tid >> 6, lane = tid & 63;
    int quad = lane >> 4, l16 = lane & 15;
    int wave_m = (w >> 1) * 64, wave_n = (w & 1) * 64;

    int rl = lane >> 3;
    int ce = (((lane & 7) << 4) ^ (rl << 4)) >> 1;
    const u16* srcA[4]; const u16* srcB[4];
    char* dstA[4]; char* dstB[4];
    #pragma unroll
    for (int i = 0; i < 4; i++) {
        int r = i * 32 + w * 8 + rl;
        srcA[i] = A    + (size_t)(bm * 128 + r) * K + ce;
        srcB[i] = Bmat + (size_t)(bn * 128 + r) * K + ce;
        dstA[i] = As + i * 4096 + w * 1024;
        dstB[i] = Bs + i * 4096 + w * 1024;
    }

    f32x4 acc[4][4] = {};
    int swz = (l16 & 7) << 4;
    for (int kt = 0; kt < K / 64; kt++) {
        int koff = kt * 64;
        #pragma unroll
        for (int i = 0; i < 4; i++) {
            gl2lds16(srcA[i] + koff, dstA[i]);
            gl2lds16(srcB[i] + koff, dstB[i]);
        }
        __syncthreads();
        #pragma unroll
        for (int ks = 0; ks < 2; ks++) {
            int cb = ks * 64 + quad * 16;
            bf16x8 av[4], bv[4];
            #pragma unroll
            for (int mi = 0; mi < 4; mi++) {
                int r = wave_m + mi * 16 + l16;
                av[mi] = *reinterpret_cast<const bf16x8*>(As + r * 128 + (cb ^ swz));
            }
            #pragma unroll
            for (int ni = 0; ni < 4; ni++) {
                int r = wave_n + ni * 16 + l16;
                bv[ni] = *reinterpret_cast<const bf16x8*>(Bs + r * 128 + (cb ^ swz));
            }
            #pragma unroll
            for (int mi = 0; mi < 4; mi++)
                #pragma unroll
                for (int ni = 0; ni < 4; ni++)
                    acc[mi][ni] = __builtin_amdgcn_mfma_f32_16x16x32_bf16(
                        av[mi], bv[ni], acc[mi][ni], 0, 0, 0);
        }
        __syncthreads();
    }

    #pragma unroll
    for (int mi = 0; mi < 4; mi++) {
        #pragma unroll
        for (int ni = 0; ni < 4; ni++) {
            int nn = bn * 128 + wave_n + ni * 16 + l16;
            float bv = (!PREDS || nn < V) ? bias[nn] : 0.f;
            #pragma unroll
            for (int r = 0; r < 4; r++) {
                int mm = bm * 128 + wave_m + mi * 16 + quad * 4 + r;
                if constexpr (PREDS) {
                    if (nn < V) {
                        int b = mm & 31, t = mm >> 5;
                        Cout[(size_t)b * T * V + (size_t)t * V + nn] = acc[mi][ni][r] + bv;
                    }
                } else {
                    Cout[(size_t)mm * ATT + nn] = acc[mi][ni][r] + bv;
                }
            }
        }
    }
}

// ---- per step: att2 = h @ Wd^T + bd (wave per output, full machine) ----
__global__ void k_att2(const u16* __restrict__ h, const float* __restrict__ Wd,
                       const float* __restrict__ bd, float* __restrict__ att2) {
    int wid = (blockIdx.x * 256 + threadIdx.x) >> 6;    // 16384 waves
    int lane = threadIdx.x & 63;
    int b = wid >> 9, a = wid & 511;
    bf16x8 hv = *reinterpret_cast<const bf16x8*>(h + b * DEC + lane * 8);
    const float4* wd = reinterpret_cast<const float4*>(Wd + (size_t)a * DEC + lane * 8);
    float4 w0 = wd[0], w1 = wd[1];
    float acc = (float)hv[0] * w0.x + (float)hv[1] * w0.y + (float)hv[2] * w0.z + (float)hv[3] * w0.w
              + (float)hv[4] * w1.x + (float)hv[5] * w1.y + (float)hv[6] * w1.z + (float)hv[7] * w1.w;
    acc = wave_sum(acc);
    if (lane == 0) att2[b * ATT + a] = acc + bd[a];
}

// ---- per step: e[b,p] = sum_a relu(att1+att2)*Wf + bf (wave per (b,p)) ----
__global__ void k_e(const float* __restrict__ att1, const float* __restrict__ att2,
                    const float* __restrict__ Wf, const float* __restrict__ bf,
                    float* __restrict__ e) {
    int wid = (blockIdx.x * 256 + threadIdx.x) >> 6;    // 6272 waves
    int lane = threadIdx.x & 63;
    int b = wid / P, p = wid % P;
    const float* a1 = att1 + ((size_t)b * P + p) * ATT + lane * 8;
    const float* a2 = att2 + b * ATT + lane * 8;
    const float* wf = Wf + lane * 8;
    float acc = 0.f;
    #pragma unroll
    for (int j = 0; j < 8; j++) {
        float v = a1[j] + a2[j];
        v = v > 0.f ? v : 0.f;
        acc += v * wf[j];
    }
    acc = wave_sum(acc);
    if (lane == 0) e[b * P + p] = acc + bf[0];
}

// ---- per step (fused): softmax (redundant per 8-block group) + awe + x build ----
__global__ __launch_bounds__(256) void k_smawe(
        const float* __restrict__ ew, const u16* __restrict__ enc_bf,
        const float* __restrict__ emb, const int* __restrict__ caps,
        u16* __restrict__ xbuf, float* __restrict__ out_alpha, int t) {
    __shared__ float sm[256];
    __shared__ float al[256];
    int bid = blockIdx.x, tid = threadIdx.x;
    int b = bid >> 3, chunk = bid & 7;
    float v = (tid < P) ? ew[b * P + tid] : -1e30f;
    sm[tid] = v; __syncthreads();
    for (int s = 128; s > 0; s >>= 1) {
        if (tid < s) sm[tid] = fmaxf(sm[tid], sm[tid + s]);
        __syncthreads();
    }
    float mx = sm[0]; __syncthreads();
    float evv = (tid < P) ? expf(v - mx) : 0.f;
    sm[tid] = evv; __syncthreads();
    for (int s = 128; s > 0; s >>= 1) {
        if (tid < s) sm[tid] += sm[tid + s];
        __syncthreads();
    }
    float inv = 1.0f / sm[0];
    float aa = evv * inv;
    al[tid] = aa;
    if (chunk == 0 && tid < P)
        out_alpha[(size_t)b * T * P + (size_t)t * P + tid] = aa;
    __syncthreads();
    int ec = (chunk << 8) + tid;
    const u16* ep = enc_bf + (size_t)b * P * ENC + ec;
    float acc = 0.f;
    #pragma unroll 4
    for (int p = 0; p < P; p++) acc += al[p] * bf2f(ep[(size_t)p * ENC]);
    xbuf[b * KX + E + ec] = f2bf(acc);
    if (chunk == 0) {
        int cap = caps[b * L + t];
        xbuf[b * KX + tid] = f2bf(emb[(size_t)cap * E + tid]);
    }
}

// ---- per step: gates partials, 4-way K-split.  grid=256, bid=kq*64+mt*32+jt ----
__global__ __launch_bounds__(256) void k_gatesK(
        const u16* __restrict__ xbuf, const u16* __restrict__ h,
        const u16* __restrict__ Wih, const u16* __restrict__ Whh,
        float* __restrict__ gpart) {
    int bid = blockIdx.x;
    int kq = bid >> 6, mt = (bid >> 5) & 1, jt = bid & 31;
    int tid = threadIdx.x, wg = tid >> 6, lane = tid & 63;
    int quad = lane >> 4, l16 = lane & 15;
    int m = mt * 16 + l16;
    int n = (wg << 9) + (jt << 4) + l16;     // 0..2047
    f32x4 acc = {0.f, 0.f, 0.f, 0.f};
    int k0 = kq * 704;                       // 704*4 = 2816 = KX + DEC
    for (int ks = 0; ks < 22; ks++) {
        int kb = k0 + ks * 32;
        bf16x8 av, bv;
        if (kb < KX) {
            av = *reinterpret_cast<const bf16x8*>(xbuf + m * KX + kb + (quad << 3));
            bv = *reinterpret_cast<const bf16x8*>(Wih + (size_t)n * KX + kb + (quad << 3));
        } else {
            av = *reinterpret_cast<const bf16x8*>(h + m * DEC + (kb - KX) + (quad << 3));
            bv = *reinterpret_cast<const bf16x8*>(Whh + (size_t)n * DEC + (kb - KX) + (quad << 3));
        }
        acc = __builtin_amdgcn_mfma_f32_16x16x32_bf16(av, bv, acc, 0, 0, 0);
    }
    #pragma unroll
    for (int r = 0; r < 4; r++) {
        int gm = mt * 16 + (quad << 2) + r;
        gpart[((kq << 5) + gm) * 2048 + n] = acc[r];
    }
}

// ---- per step: reduce partials + LSTM cell.  grid=64 (64*256 = B*DEC) ----
__global__ void k_cell(const float* __restrict__ gpart,
                       const float* __restrict__ bih, const float* __restrict__ bhh,
                       float* __restrict__ cbuf, u16* __restrict__ hn,
                       u16* __restrict__ hall, int t) {
    int gtid = blockIdx.x * 256 + threadIdx.x;   // 0..16383
    int d = gtid & 511;
    int b = gtid >> 9;
    float g0 = bih[d]        + bhh[d];
    float g1 = bih[512 + d]  + bhh[512 + d];
    float g2 = bih[1024 + d] + bhh[1024 + d];
    float g3 = bih[1536 + d] + bhh[1536 + d];
    #pragma unroll
    for (int kq = 0; kq < 4; kq++) {
        const float* gp = gpart + ((kq << 5) + b) * 2048;
        g0 += gp[d]; g1 += gp[512 + d]; g2 += gp[1024 + d]; g3 += gp[1536 + d];
    }
    float gi = sigf(g0), gf = sigf(g1), gg = tanhf(g2), go = sigf(g3);
    float cn = gf * cbuf[gtid] + gi * gg;
    cbuf[gtid] = cn;
    u16 hbv = f2bf(go * tanhf(cn));
    hn[gtid] = hbv;
    hall[(size_t)t * B * DEC + gtid] = hbv;
}

extern "C" void kernel_launch(void* const* d_in, const int* in_sizes, int n_in,
                              void* d_out, int out_size, void* d_ws, size_t ws_size,
                              hipStream_t stream) {
    const float* enc  = (const float*)d_in[0];
    const int*   caps = (const int*)d_in[1];
    // d_in[2] caption_lengths: unused by reference output
    const float* emb  = (const float*)d_in[3];
    const float* We   = (const float*)d_in[4];
    const float* be   = (const float*)d_in[5];
    const float* Wd   = (const float*)d_in[6];
    const float* bd   = (const float*)d_in[7];
    const float* Wf   = (const float*)d_in[8];
    const float* bfa  = (const float*)d_in[9];
    const float* Wih  = (const float*)d_in[10];
    const float* bih  = (const float*)d_in[11];
    const float* Whh  = (const float*)d_in[12];
    const float* bhh  = (const float*)d_in[13];
    const float* Wfc  = (const float*)d_in[14];
    const float* bfc  = (const float*)d_in[15];
    const float* Wh0  = (const float*)d_in[16];
    const float* bh0  = (const float*)d_in[17];
    const float* Wc0  = (const float*)d_in[18];
    const float* bc0  = (const float*)d_in[19];

    float* out_preds = (float*)d_out;
    float* out_alpha = (float*)d_out + (size_t)B * T * V;

    char* w = (char*)d_ws;
    size_t off = 0;
    auto carve = [&](size_t bytes) -> void* {
        void* p = w + off;
        off = (off + bytes + 255) & ~(size_t)255;
        return p;
    };
    u16*   enc_bf = (u16*)  carve((size_t)B * P * ENC * 2);        // 25.7 MB
    u16*   We_bf  = (u16*)  carve((size_t)ATT * ENC * 2);          //  2.1 MB
    u16*   Wih_bf = (u16*)  carve((size_t)4 * DEC * KX * 2);       //  9.4 MB
    u16*   Whh_bf = (u16*)  carve((size_t)4 * DEC * DEC * 2);      //  2.1 MB
    u16*   Wfc_bf = (u16*)  carve((size_t)VPAD * DEC * 2);         // 30.8 MB
    float* att1   = (float*)carve((size_t)B * P * ATT * 4);        // 12.85 MB
    float* meanb  = (float*)carve((size_t)B * ENC * 4);
    float* att2w  = (float*)carve((size_t)B * ATT * 4);
    float* ebuf   = (float*)carve((size_t)B * P * 4);
    u16*   xbuf   = (u16*)  carve((size_t)B * KX * 2);
    u16*   hb0    = (u16*)  carve((size_t)B * DEC * 2);
    u16*   hb1    = (u16*)  carve((size_t)B * DEC * 2);
    float* cbuf   = (float*)carve((size_t)B * DEC * 4);
    u16*   hall   = (u16*)  carve((size_t)T * B * DEC * 2);        // 0.66 MB
    float* gpart  = (float*)carve((size_t)4 * B * 4 * DEC * 4);    // 1 MB
    (void)ws_size; (void)n_in; (void)in_sizes; (void)out_size;

    // one-time: bf16 conversions
    k_f2b4<<<(B * P * ENC) / 1024, 256, 0, stream>>>(enc, enc_bf, (B * P * ENC) / 4);
    k_f2b4<<<(ATT * ENC) / 1024, 256, 0, stream>>>(We, We_bf, (ATT * ENC) / 4);
    k_f2b4<<<(4 * DEC * KX) / 1024, 256, 0, stream>>>(Wih, Wih_bf, (4 * DEC * KX) / 4);
    k_f2b4<<<(4 * DEC * DEC) / 1024, 256, 0, stream>>>(Whh, Whh_bf, (4 * DEC * DEC) / 4);
    k_f2b4<<<(V * DEC) / 1024, 256, 0, stream>>>(Wfc, Wfc_bf, (V * DEC) / 4);
    k_zero16<<<((VPAD - V) * DEC) / 256, 256, 0, stream>>>(Wfc_bf + (size_t)V * DEC, (VPAD - V) * DEC);

    // init phase
    k_mean<<<(B * ENC) / 256, 256, 0, stream>>>(enc, meanb);
    k_h0c0<<<(B * 2 * DEC * 64) / 256, 256, 0, stream>>>(meanb, Wh0, bh0, Wc0, bc0, hb0, cbuf);
    k_gemm128<ENC, false><<<(B * P / 128) * (ATT / 128), 256, 0, stream>>>(enc_bf, We_bf, be, att1);

    // 20 sequential decode steps, 5 launches each, all grids sized for the full machine
    for (int t = 0; t < T; t++) {
        const u16* hin = (t & 1) ? hb1 : hb0;
        u16* hnx = (t & 1) ? hb0 : hb1;
        k_att2  <<<(B * ATT * 64) / 256, 256, 0, stream>>>(hin, Wd, bd, att2w);
        k_e     <<<(B * P * 64) / 256, 256, 0, stream>>>(att1, att2w, Wf, bfa, ebuf);
        k_smawe <<<B * 8, 256, 0, stream>>>(ebuf, enc_bf, emb, caps, xbuf, out_alpha, t);
        k_gatesK<<<256, 256, 0, stream>>>(xbuf, hin, Wih_bf, Whh_bf, gpart);
        k_cell  <<<64, 256, 0, stream>>>(gpart, bih, bhh, cbuf, hnx, hall, t);
    }

    // batched preds: [T*B, DEC] @ Wfc^T -> out[b, t, :]
    k_gemm128<DEC, true><<<5 * (VPAD / 128), 256, 0, stream>>>(hall, Wfc_bf, bfc, out_preds);
}